// Round 3
// baseline (545.292 us; speedup 1.0000x reference)
//
#include <hip/hip_runtime.h>
#include <hip/hip_bf16.h>

#define D 64
#define PAD 65   // LDS tile leading-dim pad: stride-65 words -> conflict-free transpose

// ---- CSR build ------------------------------------------------------------
// Harness delivers integer inputs as int32 (edge_index -> const int*).

__global__ void count_k(const int* __restrict__ dst, int* __restrict__ cnt, int E) {
    int e = blockIdx.x * blockDim.x + threadIdx.x;
    if (e < E) atomicAdd(&cnt[dst[e]], 1);
}

// Single-block scan (1024 thr): exclusive prefix-sum of cnt -> rowptr/cursor.
// Also transposes the 4 weight matrices into Wt[k][f] layout (independent work).
__global__ __launch_bounds__(1024) void scan_k(
    const int* __restrict__ cnt, int* __restrict__ rowptr, int* __restrict__ cursor,
    const float* __restrict__ Wl1, const float* __restrict__ Wr1,
    const float* __restrict__ Wl2, const float* __restrict__ Wr2,
    float* __restrict__ Wt, int N, int E)
{
    int tid = threadIdx.x;
    for (int i = tid; i < 4096; i += 1024) {       // Wt[m][k*64+f] = W[m][f*64+k]
        int f = i >> 6, k = i & 63;
        Wt[0 * 4096 + k * 64 + f] = Wl1[i];
        Wt[1 * 4096 + k * 64 + f] = Wr1[i];
        Wt[2 * 4096 + k * 64 + f] = Wl2[i];
        Wt[3 * 4096 + k * 64 + f] = Wr2[i];
    }
    __shared__ int wsum[16];
    int lane = tid & 63, wid = tid >> 6;
    int carry = 0;
    for (int base = 0; base < N; base += 1024) {
        int gid = base + tid;
        int v0 = (gid < N) ? cnt[gid] : 0;
        int v = v0;
        #pragma unroll
        for (int off = 1; off < 64; off <<= 1) {   // wave-inclusive scan, no barriers
            int t = __shfl_up(v, off, 64);
            if (lane >= off) v += t;
        }
        if (lane == 63) wsum[wid] = v;
        __syncthreads();
        if (wid == 0) {
            int s = (lane < 16) ? wsum[lane] : 0;
            #pragma unroll
            for (int off = 1; off < 16; off <<= 1) {
                int t = __shfl_up(s, off, 64);
                if (lane >= off) s += t;
            }
            if (lane < 16) wsum[lane] = s;         // inclusive wave sums
        }
        __syncthreads();
        int waveOff = (wid == 0) ? 0 : wsum[wid - 1];
        int excl = carry + waveOff + (v - v0);
        if (gid < N) { rowptr[gid] = excl; cursor[gid] = excl; }
        carry += wsum[15];
        __syncthreads();                            // wsum reuse next chunk
    }
    if (tid == 0) rowptr[N] = E;
}

__global__ void fill_k(const int* __restrict__ src, const int* __restrict__ dst,
                       int* __restrict__ cursor, int* __restrict__ col, int E) {
    int e = blockIdx.x * blockDim.x + threadIdx.x;
    if (e < E) {
        int d = dst[e];
        int pos = atomicAdd(&cursor[d], 1);
        col[pos] = src[e];
    }
}

// ---- aggregation: wave-per-node mean gather, no LDS, 8 outstanding loads ----

__global__ __launch_bounds__(256) void agg_k(
    const float* __restrict__ xin, const int* __restrict__ rowptr,
    const int* __restrict__ col, float* __restrict__ agg, int N)
{
    const int lane = threadIdx.x & 63;
    const int n = blockIdx.x * (blockDim.x >> 6) + (threadIdx.x >> 6);
    if (n >= N) return;
    const int beg = rowptr[n], end = rowptr[n + 1];
    float a0 = 0.f, a1 = 0.f, a2 = 0.f, a3 = 0.f;
    float a4 = 0.f, a5 = 0.f, a6 = 0.f, a7 = 0.f;
    int j = beg;
    for (; j + 8 <= end; j += 8) {                 // 8 coalesced 256B gathers in flight
        int c0 = col[j + 0], c1 = col[j + 1], c2 = col[j + 2], c3 = col[j + 3];
        int c4 = col[j + 4], c5 = col[j + 5], c6 = col[j + 6], c7 = col[j + 7];
        a0 += xin[(size_t)c0 * D + lane];
        a1 += xin[(size_t)c1 * D + lane];
        a2 += xin[(size_t)c2 * D + lane];
        a3 += xin[(size_t)c3 * D + lane];
        a4 += xin[(size_t)c4 * D + lane];
        a5 += xin[(size_t)c5 * D + lane];
        a6 += xin[(size_t)c6 * D + lane];
        a7 += xin[(size_t)c7 * D + lane];
    }
    for (; j < end; ++j) a0 += xin[(size_t)col[j] * D + lane];
    float s = ((a0 + a1) + (a2 + a3)) + ((a4 + a5) + (a6 + a7));
    s *= 1.0f / fmaxf((float)(end - beg), 1.0f);   // mean with deg>=1 guard
    agg[(size_t)n * D + lane] = s;
}

// ---- MLP: out = Wl*agg + b + Wr*x (+tanh), lane=node 64-node tiles ----------
// One wave per tile. Inputs transposed through padded LDS; weights (pre-
// transposed Wt[k][f]) staged in LDS and broadcast-read as float4 (uniform
// address = free broadcast). 64 independent FMA chains per lane.

__device__ __forceinline__ float tanh_fast(float v) {
    float e = __expf(2.f * v);                     // v_exp; inf-safe at extremes
    return 1.f - 2.f * __builtin_amdgcn_rcpf(e + 1.f);
}

template <bool TANH>
__global__ __launch_bounds__(64) void mlp_k(
    const float* __restrict__ agg, const float* __restrict__ xin,
    const float* __restrict__ WtL, const float* __restrict__ WtR,
    const float* __restrict__ bias, float* __restrict__ out, int N)
{
    __shared__ float T[64 * PAD];                  // 16.6 KB tile buffer
    __shared__ float WL[4096];                     // 16 KB
    __shared__ float WR[4096];                     // 16 KB  (total 48.6 KB -> 3 blk/CU)
    const int lane = threadIdx.x;
    const int n0 = blockIdx.x * 64;

    for (int i = lane; i < 4096; i += 64) { WL[i] = WtL[i]; WR[i] = WtR[i]; }
    for (int i = 0; i < 64; ++i) {                 // agg tile, row-coalesced
        int n = n0 + i;
        T[i * PAD + lane] = (n < N) ? agg[(size_t)n * D + lane] : 0.f;
    }
    __syncthreads();

    float acc[D];
    #pragma unroll
    for (int f = 0; f < D; ++f) acc[f] = bias[f];  // uniform -> s_load

    for (int k = 0; k < D; ++k) {                  // pass 1: Wl * agg
        float a = T[lane * PAD + k];               // stride-65: conflict-free
        const float4* wrow = (const float4*)&WL[k << 6];
        #pragma unroll
        for (int q = 0; q < 16; ++q) {
            float4 w = wrow[q];                    // uniform addr: b128 broadcast
            acc[4 * q + 0] = fmaf(w.x, a, acc[4 * q + 0]);
            acc[4 * q + 1] = fmaf(w.y, a, acc[4 * q + 1]);
            acc[4 * q + 2] = fmaf(w.z, a, acc[4 * q + 2]);
            acc[4 * q + 3] = fmaf(w.w, a, acc[4 * q + 3]);
        }
    }

    __syncthreads();
    for (int i = 0; i < 64; ++i) {                 // x tile
        int n = n0 + i;
        T[i * PAD + lane] = (n < N) ? xin[(size_t)n * D + lane] : 0.f;
    }
    __syncthreads();

    for (int k = 0; k < D; ++k) {                  // pass 2: Wr * x
        float a = T[lane * PAD + k];
        const float4* wrow = (const float4*)&WR[k << 6];
        #pragma unroll
        for (int q = 0; q < 16; ++q) {
            float4 w = wrow[q];
            acc[4 * q + 0] = fmaf(w.x, a, acc[4 * q + 0]);
            acc[4 * q + 1] = fmaf(w.y, a, acc[4 * q + 1]);
            acc[4 * q + 2] = fmaf(w.z, a, acc[4 * q + 2]);
            acc[4 * q + 3] = fmaf(w.w, a, acc[4 * q + 3]);
        }
    }

    if (TANH) {
        #pragma unroll
        for (int f = 0; f < D; ++f) acc[f] = tanh_fast(acc[f]);
    }

    __syncthreads();
    #pragma unroll
    for (int f = 0; f < D; ++f) T[lane * PAD + f] = acc[f];  // transpose out
    __syncthreads();
    for (int i = 0; i < 64; ++i) {
        int n = n0 + i;
        if (n < N) out[(size_t)n * D + lane] = T[i * PAD + lane];
    }
}

// ---- launcher ---------------------------------------------------------------

extern "C" void kernel_launch(void* const* d_in, const int* in_sizes, int n_in,
                              void* d_out, int out_size, void* d_ws, size_t ws_size,
                              hipStream_t stream) {
    const float* x   = (const float*)d_in[0];
    const int*   ei  = (const int*)d_in[1];     // int64 in ref -> int32 here
    const float* Wl1 = (const float*)d_in[2];
    const float* bl1 = (const float*)d_in[3];
    const float* Wr1 = (const float*)d_in[4];
    const float* Wl2 = (const float*)d_in[5];
    const float* bl2 = (const float*)d_in[6];
    const float* Wr2 = (const float*)d_in[7];

    const int N = in_sizes[0] / D;
    const int E = in_sizes[1] / 2;
    const int* srcI = ei;        // edge_index[0]
    const int* dstI = ei + E;    // edge_index[1]

    auto al = [](size_t v) { return (v + 255) & ~(size_t)255; };
    char* w = (char*)d_ws;
    size_t off = 0;
    int*   cnt    = (int*)(w + off);  off += al((size_t)N * 4);
    int*   rowptr = (int*)(w + off);  off += al((size_t)(N + 1) * 4);
    int*   cursor = (int*)(w + off);  off += al((size_t)N * 4);
    float* Wt     = (float*)(w + off); off += al((size_t)4 * 4096 * 4);
    int*   colA   = (int*)(w + off);  off += al((size_t)E * 4);
    float* h      = (float*)(w + off);  // [N, D] fp32 layer-1 output

    float* aggbuf = (float*)d_out;    // d_out doubles as the agg scratch:
                                      // mlp reads its own tile rows fully
                                      // before writing them (in-place safe).
    float* out = (float*)d_out;

    const int EB = (E + 255) / 256;
    const int AB = (N + 3) / 4;        // agg_k: 4 waves/block, 1 node/wave
    const int MB = (N + 63) / 64;      // mlp_k: 1 wave/block, 64 nodes/tile

    hipMemsetAsync(cnt, 0, (size_t)N * 4, stream);
    count_k<<<EB, 256, 0, stream>>>(dstI, cnt, E);
    scan_k<<<1, 1024, 0, stream>>>(cnt, rowptr, cursor, Wl1, Wr1, Wl2, Wr2, Wt, N, E);
    fill_k<<<EB, 256, 0, stream>>>(srcI, dstI, cursor, colA, E);

    // layer 1
    agg_k<<<AB, 256, 0, stream>>>(x, rowptr, colA, aggbuf, N);
    mlp_k<true ><<<MB, 64, 0, stream>>>(aggbuf, x, Wt + 0 * 4096, Wt + 1 * 4096, bl1, h, N);
    // layer 2
    agg_k<<<AB, 256, 0, stream>>>(h, rowptr, colA, aggbuf, N);
    mlp_k<false><<<MB, 64, 0, stream>>>(aggbuf, h, Wt + 2 * 4096, Wt + 3 * 4096, bl2, out, N);
}

// Round 4
// 294.810 us; speedup vs baseline: 1.8496x; 1.8496x over previous
//
#include <hip/hip_runtime.h>
#include <hip/hip_bf16.h>

#define D 64

// ---- CSR build ------------------------------------------------------------
// Harness delivers integer inputs as int32 (edge_index -> const int*).

__global__ void count_k(const int* __restrict__ dst, int* __restrict__ cnt, int E) {
    int e0 = (blockIdx.x * blockDim.x + threadIdx.x) * 4;
    if (e0 + 4 <= E) {
        int4 d = *(const int4*)(dst + e0);
        atomicAdd(&cnt[d.x], 1); atomicAdd(&cnt[d.y], 1);
        atomicAdd(&cnt[d.z], 1); atomicAdd(&cnt[d.w], 1);
    } else {
        for (int e = e0; e < E; ++e) atomicAdd(&cnt[dst[e]], 1);
    }
}

__global__ void scanA_k(const int* __restrict__ cnt, int* __restrict__ rowptr,
                        int* __restrict__ bsum, int N) {
    __shared__ int tmp[256];
    int gid = blockIdx.x * 256 + threadIdx.x;
    int v = (gid < N) ? cnt[gid] : 0;
    tmp[threadIdx.x] = v;
    __syncthreads();
    for (int off = 1; off < 256; off <<= 1) {
        int t = (threadIdx.x >= off) ? tmp[threadIdx.x - off] : 0;
        __syncthreads();
        tmp[threadIdx.x] += t;
        __syncthreads();
    }
    if (gid < N) rowptr[gid] = tmp[threadIdx.x] - v;   // exclusive within block
    if (threadIdx.x == 255) bsum[blockIdx.x] = tmp[255];
}

__global__ void scanB_k(int* __restrict__ bsum, int nb) {  // nb <= 256
    __shared__ int tmp[256];
    int v = (threadIdx.x < nb) ? bsum[threadIdx.x] : 0;
    tmp[threadIdx.x] = v;
    __syncthreads();
    for (int off = 1; off < 256; off <<= 1) {
        int t = (threadIdx.x >= off) ? tmp[threadIdx.x - off] : 0;
        __syncthreads();
        tmp[threadIdx.x] += t;
        __syncthreads();
    }
    if (threadIdx.x < nb) bsum[threadIdx.x] = tmp[threadIdx.x] - v;  // exclusive
}

__global__ void scanC_k(int* __restrict__ rowptr, int* __restrict__ cursor,
                        const int* __restrict__ bsum, int N, int E) {
    int gid = blockIdx.x * 256 + threadIdx.x;
    if (gid < N) {
        int v = rowptr[gid] + bsum[blockIdx.x];
        rowptr[gid] = v;
        cursor[gid] = v;
    }
    if (blockIdx.x == 0 && threadIdx.x == 0) rowptr[N] = E;
}

__global__ void fill_k(const int* __restrict__ src, const int* __restrict__ dst,
                       int* __restrict__ cursor, int* __restrict__ col, int E) {
    int e0 = (blockIdx.x * blockDim.x + threadIdx.x) * 4;
    if (e0 + 4 <= E) {
        int4 d = *(const int4*)(dst + e0);
        int4 s = *(const int4*)(src + e0);
        col[atomicAdd(&cursor[d.x], 1)] = s.x;
        col[atomicAdd(&cursor[d.y], 1)] = s.y;
        col[atomicAdd(&cursor[d.z], 1)] = s.z;
        col[atomicAdd(&cursor[d.w], 1)] = s.w;
    } else {
        for (int e = e0; e < E; ++e)
            col[atomicAdd(&cursor[dst[e]], 1)] = src[e];
    }
}

// ---- aggregation: wave-per-node mean gather, no LDS, 8 outstanding loads ----

__global__ __launch_bounds__(256) void agg_k(
    const float* __restrict__ xin, const int* __restrict__ rowptr,
    const int* __restrict__ col, float* __restrict__ agg, int N)
{
    const int lane = threadIdx.x & 63;
    const int n = blockIdx.x * (blockDim.x >> 6) + (threadIdx.x >> 6);
    if (n >= N) return;
    const int beg = rowptr[n], end = rowptr[n + 1];
    float a0 = 0.f, a1 = 0.f, a2 = 0.f, a3 = 0.f;
    float a4 = 0.f, a5 = 0.f, a6 = 0.f, a7 = 0.f;
    int j = beg;
    for (; j + 8 <= end; j += 8) {                 // 8 coalesced 256B gathers in flight
        int c0 = col[j + 0], c1 = col[j + 1], c2 = col[j + 2], c3 = col[j + 3];
        int c4 = col[j + 4], c5 = col[j + 5], c6 = col[j + 6], c7 = col[j + 7];
        a0 += xin[(size_t)c0 * D + lane];
        a1 += xin[(size_t)c1 * D + lane];
        a2 += xin[(size_t)c2 * D + lane];
        a3 += xin[(size_t)c3 * D + lane];
        a4 += xin[(size_t)c4 * D + lane];
        a5 += xin[(size_t)c5 * D + lane];
        a6 += xin[(size_t)c6 * D + lane];
        a7 += xin[(size_t)c7 * D + lane];
    }
    for (; j < end; ++j) a0 += xin[(size_t)col[j] * D + lane];
    float s = ((a0 + a1) + (a2 + a3)) + ((a4 + a5) + (a6 + a7));
    s *= 1.0f / fmaxf((float)(end - beg), 1.0f);   // mean with deg>=1 guard
    agg[(size_t)n * D + lane] = s;
}

// ---- MLP: thread-per-node, acc[64] in VGPRs, W rows broadcast from LDS ------
// out[n][f] = bias[f] + sum_k Wl[f][k]*agg[n][k] + sum_k Wr[f][k]*x[n][k]
// W read in ORIGINAL row-major layout: per (kc,f) a contiguous float4 at a
// wave-uniform LDS address -> pure broadcast, no conflicts, no transpose.

__device__ __forceinline__ float tanh_fast(float v) {
    float e = __expf(2.f * v);                     // inf-safe at extremes
    return 1.f - 2.f * __builtin_amdgcn_rcpf(e + 1.f);
}

template <bool TANH>
__global__ __launch_bounds__(128) void mlp_k(
    const float* __restrict__ agg, const float* __restrict__ xin,
    const float* __restrict__ Wl, const float* __restrict__ Wr,
    const float* __restrict__ bias, float* __restrict__ out, int N)
{
    __shared__ float WLs[D * D];                   // 16 KB
    __shared__ float WRs[D * D];                   // 16 KB
    for (int i = threadIdx.x; i < D * D; i += 128) { WLs[i] = Wl[i]; WRs[i] = Wr[i]; }
    __syncthreads();

    const int n = blockIdx.x * 128 + threadIdx.x;
    if (n >= N) return;                            // no barriers after this point

    float acc[D];
    #pragma unroll
    for (int f = 0; f < D; ++f) acc[f] = bias[f];

    const float4* av = (const float4*)(agg + (size_t)n * D);
    for (int kc = 0; kc < 16; ++kc) {              // rolled: keeps I$ small
        float4 a = av[kc];
        #pragma unroll
        for (int f = 0; f < D; ++f) {              // 64 ds_read_b128 (broadcast) + 256 FMA
            float4 w = *(const float4*)&WLs[(f << 6) + (kc << 2)];
            acc[f] = fmaf(a.w, w.w, fmaf(a.z, w.z, fmaf(a.y, w.y, fmaf(a.x, w.x, acc[f]))));
        }
    }
    const float4* xv = (const float4*)(xin + (size_t)n * D);
    for (int kc = 0; kc < 16; ++kc) {
        float4 a = xv[kc];
        #pragma unroll
        for (int f = 0; f < D; ++f) {
            float4 w = *(const float4*)&WRs[(f << 6) + (kc << 2)];
            acc[f] = fmaf(a.w, w.w, fmaf(a.z, w.z, fmaf(a.y, w.y, fmaf(a.x, w.x, acc[f]))));
        }
    }

    if (TANH) {
        #pragma unroll
        for (int f = 0; f < D; ++f) acc[f] = tanh_fast(acc[f]);
    }

    float4* ov = (float4*)(out + (size_t)n * D);
    #pragma unroll
    for (int kc = 0; kc < 16; ++kc)
        ov[kc] = make_float4(acc[4 * kc], acc[4 * kc + 1], acc[4 * kc + 2], acc[4 * kc + 3]);
}

// ---- launcher ---------------------------------------------------------------

extern "C" void kernel_launch(void* const* d_in, const int* in_sizes, int n_in,
                              void* d_out, int out_size, void* d_ws, size_t ws_size,
                              hipStream_t stream) {
    const float* x   = (const float*)d_in[0];
    const int*   ei  = (const int*)d_in[1];     // int64 in ref -> int32 here
    const float* Wl1 = (const float*)d_in[2];
    const float* bl1 = (const float*)d_in[3];
    const float* Wr1 = (const float*)d_in[4];
    const float* Wl2 = (const float*)d_in[5];
    const float* bl2 = (const float*)d_in[6];
    const float* Wr2 = (const float*)d_in[7];

    const int N = in_sizes[0] / D;
    const int E = in_sizes[1] / 2;
    const int* srcI = ei;        // edge_index[0]
    const int* dstI = ei + E;    // edge_index[1]

    auto al = [](size_t v) { return (v + 255) & ~(size_t)255; };
    char* w = (char*)d_ws;
    size_t off = 0;
    int*   cnt    = (int*)(w + off);  off += al((size_t)N * 4);
    int*   rowptr = (int*)(w + off);  off += al((size_t)(N + 1) * 4);
    int*   cursor = (int*)(w + off);  off += al((size_t)N * 4);
    int*   bsum   = (int*)(w + off);  off += al(1024);
    int*   colA   = (int*)(w + off);  off += al((size_t)E * 4);
    float* h      = (float*)(w + off);  // [N, D] fp32 layer-1 output

    float* aggbuf = (float*)d_out;    // agg scratch; mlp_k reads its node's row
                                      // fully into registers before overwriting
    float* out = (float*)d_out;

    const int NB = (N + 255) / 256;          // 196 <= 256, scanB handles it
    const int EB4 = (E / 4 + 255) / 256;     // int4 edge kernels
    const int AB = (N + 3) / 4;              // agg_k: 4 waves/block, 1 node/wave
    const int MB = (N + 127) / 128;          // mlp_k: thread-per-node

    hipMemsetAsync(cnt, 0, (size_t)N * 4, stream);
    count_k<<<EB4, 256, 0, stream>>>(dstI, cnt, E);
    scanA_k<<<NB, 256, 0, stream>>>(cnt, rowptr, bsum, N);
    scanB_k<<<1, 256, 0, stream>>>(bsum, NB);
    scanC_k<<<NB, 256, 0, stream>>>(rowptr, cursor, bsum, N, E);
    fill_k<<<EB4, 256, 0, stream>>>(srcI, dstI, cursor, colA, E);

    // layer 1
    agg_k<<<AB, 256, 0, stream>>>(x, rowptr, colA, aggbuf, N);
    mlp_k<true ><<<MB, 128, 0, stream>>>(aggbuf, x, Wl1, Wr1, bl1, h, N);
    // layer 2
    agg_k<<<AB, 256, 0, stream>>>(h, rowptr, colA, aggbuf, N);
    mlp_k<false><<<MB, 128, 0, stream>>>(aggbuf, h, Wl2, Wr2, bl2, out, N);
}